// Round 5
// baseline (27069.067 us; speedup 1.0000x reference)
//
#include <hip/hip_runtime.h>
#include <stdint.h>

typedef __attribute__((ext_vector_type(4))) float f32x4;
typedef __attribute__((ext_vector_type(8))) short s16x8;
typedef unsigned short ushort_t;

#define DEVINL static __device__ __forceinline__

DEVINL ushort_t f2bf(float f) {
  unsigned int u = __float_as_uint(f);
  u += 0x7FFFu + ((u >> 16) & 1u);            // RNE
  return (ushort_t)(u >> 16);
}
DEVINL float bf2f(ushort_t h) {
  return __uint_as_float(((unsigned int)h) << 16);
}
DEVINL void split2(float v, ushort_t& hi, ushort_t& lo) {
  hi = f2bf(v);
  lo = f2bf(v - bf2f(hi));                    // combined rel err ~2^-17
}
DEVINL float sigf(float x)   { return 1.f / (1.f + __expf(-x)); }
DEVINL float tanhf_(float x) { return 1.f - 2.f / (__expf(2.f * x) + 1.f); }  // stable both tails

// ---------------- prep: reorder rows into G = hcol*4 + gate; split w_hh ----------------
__global__ __launch_bounds__(256) void k_prep(
    const float* __restrict__ wih,   // [4096][512]  rows: gate*1024 + hcol
    const float* __restrict__ whh,   // [4096][1024]
    const float* __restrict__ b,     // [4096]
    float* __restrict__ wihR,        // [4096][512]  rows: hcol*4 + gate
    float* __restrict__ biasR,       // [4096]
    ushort_t* __restrict__ whhR_hi,  // [4096][1024]
    ushort_t* __restrict__ whhR_lo)
{
  int hcol = blockIdx.x;             // 0..1023
  int tid = threadIdx.x;
  for (int g = 0; g < 4; ++g) {
    int G = hcol * 4 + g;
    int orig = g * 1024 + hcol;
    const float* src_ih = wih + (size_t)orig * 512;
    float* dst_ih = wihR + (size_t)G * 512;
    dst_ih[tid] = src_ih[tid];
    dst_ih[tid + 256] = src_ih[tid + 256];
    const float* src_hh = whh + (size_t)orig * 1024;
    ushort_t* dh = whhR_hi + (size_t)G * 1024;
    ushort_t* dl = whhR_lo + (size_t)G * 1024;
#pragma unroll
    for (int r = 0; r < 4; ++r) {
      int j = tid + r * 256;
      ushort_t h_, l_;
      split2(src_hh[j], h_, l_);
      dh[j] = h_; dl[j] = l_;
    }
    if (tid == 0) biasR[G] = b[orig];
  }
}

// ---------------- xproj split-bf16 GEMM (one T-chunk of 128) ----------------
// C = x[:, c*128 : c*128+128] @ wihR^T + biasR -> fp32 xp [128][64][4096(G)]
__global__ __launch_bounds__(256) void k_gemm_chunk(
    const float* __restrict__ x,     // [64][1024][512]
    const float* __restrict__ wihR,  // [4096][512] (G-ordered rows)
    const float* __restrict__ biasR, // [4096]
    float* __restrict__ xp,          // [128][64][4096]
    int chunk)
{
  __shared__ __align__(16) ushort_t Ah[128 * 64], Al[128 * 64];
  __shared__ __align__(16) ushort_t Bh[128 * 64], Bl[128 * 64];
  const int K = 512;
  int bid = blockIdx.x;
  int ntile = bid & 31, mtile = bid >> 5;     // 32 ntiles (N=4096), 64 mtiles (M=8192)
  int m0 = mtile * 128, n0 = ntile * 128;
  int tid = threadIdx.x, lane = tid & 63, wv = tid >> 6;
  int wm = wv >> 1, wn = wv & 1;              // 2x2 waves, 64x64 each
  int lm = lane & 15, lk = lane >> 4;
  int sr = tid >> 3;                          // staging row 0..31
  int sc = (tid & 7) * 8;                     // staging col (elements)

  f32x4 acc[4][4] = {};
  float ax[4][8], bx[4][8];

#pragma unroll
  for (int p = 0; p < 4; ++p) {
    int am = m0 + p * 32 + sr;                // bat = am>>7, tl = am&127
    const float* ap = x + (size_t)((am >> 7) * 1024 + chunk * 128 + (am & 127)) * K + sc;
    const float* bp = wihR + (size_t)(n0 + p * 32 + sr) * K + sc;
#pragma unroll
    for (int e = 0; e < 8; ++e) ax[p][e] = ap[e];
#pragma unroll
    for (int e = 0; e < 8; ++e) bx[p][e] = bp[e];
  }

  for (int k0 = 0; k0 < K; k0 += 64) {
    __syncthreads();
#pragma unroll
    for (int p = 0; p < 4; ++p) {
      s16x8 vah, val, vbh, vbl;
#pragma unroll
      for (int e = 0; e < 8; ++e) {
        ushort_t h_, l_;
        split2(ax[p][e], h_, l_); vah[e] = (short)h_; val[e] = (short)l_;
        split2(bx[p][e], h_, l_); vbh[e] = (short)h_; vbl[e] = (short)l_;
      }
      int rw = p * 32 + sr;
      int wb = (rw * 128 + sc * 2) ^ ((rw & 7) << 4);   // XOR swizzle, 16B-aligned
      *(s16x8*)((char*)Ah + wb) = vah;
      *(s16x8*)((char*)Al + wb) = val;
      *(s16x8*)((char*)Bh + wb) = vbh;
      *(s16x8*)((char*)Bl + wb) = vbl;
    }
    __syncthreads();
    if (k0 + 64 < K) {
#pragma unroll
      for (int p = 0; p < 4; ++p) {
        int am = m0 + p * 32 + sr;
        const float* ap = x + (size_t)((am >> 7) * 1024 + chunk * 128 + (am & 127)) * K + (k0 + 64) + sc;
        const float* bp = wihR + (size_t)(n0 + p * 32 + sr) * K + (k0 + 64) + sc;
#pragma unroll
        for (int e = 0; e < 8; ++e) ax[p][e] = ap[e];
#pragma unroll
        for (int e = 0; e < 8; ++e) bx[p][e] = bp[e];
      }
    }
#pragma unroll
    for (int kk = 0; kk < 2; ++kk) {
      s16x8 fah[4], fal[4], fbh[4], fbl[4];
      int cb = (kk * 32 + lk * 8) * 2;
#pragma unroll
      for (int i = 0; i < 4; ++i) {
        int rA = wm * 64 + i * 16 + lm;
        int rB = wn * 64 + i * 16 + lm;
        int oa = (rA * 128 + cb) ^ ((rA & 7) << 4);
        int ob = (rB * 128 + cb) ^ ((rB & 7) << 4);
        fah[i] = *(const s16x8*)((const char*)Ah + oa);
        fal[i] = *(const s16x8*)((const char*)Al + oa);
        fbh[i] = *(const s16x8*)((const char*)Bh + ob);
        fbl[i] = *(const s16x8*)((const char*)Bl + ob);
      }
#pragma unroll
      for (int i = 0; i < 4; ++i)
#pragma unroll
        for (int j = 0; j < 4; ++j) {
          acc[i][j] = __builtin_amdgcn_mfma_f32_16x16x32_bf16(fah[i], fbh[j], acc[i][j], 0, 0, 0);
          acc[i][j] = __builtin_amdgcn_mfma_f32_16x16x32_bf16(fah[i], fbl[j], acc[i][j], 0, 0, 0);
          acc[i][j] = __builtin_amdgcn_mfma_f32_16x16x32_bf16(fal[i], fbh[j], acc[i][j], 0, 0, 0);
        }
    }
  }
#pragma unroll
  for (int j = 0; j < 4; ++j) {
    int G = n0 + wn * 64 + j * 16 + lm;
    float bv = biasR[G];
#pragma unroll
    for (int i = 0; i < 4; ++i) {
      int mb = m0 + wm * 64 + i * 16 + lk * 4;
#pragma unroll
      for (int r = 0; r < 4; ++r) {
        int m = mb + r;                      // bat = m>>7, tl = m&127
        xp[((size_t)(m & 127) * 64 + (m >> 7)) * 4096 + G] = acc[i][j][r] + bv;
      }
    }
  }
}

// ---------------- one LSTM timestep ----------------
// 128 WGs x 256 thr. WG w owns G-cols [32w, 32w+32) = hcols [8w, 8w+8).
// Wave q: m-tile q (bats 16q..16q+16), both 16-wide n-tiles. 3-term split GEMM from
// global (L2/LLC-hot) h planes + whhR planes, then fused gate/cell update.
__global__ __launch_bounds__(256) void k_step(
    const float* __restrict__ xp,           // [128][64][4096]
    const ushort_t* __restrict__ whh_hi,    // [4096][1024]
    const ushort_t* __restrict__ whh_lo,
    const ushort_t* __restrict__ hs_hi,     // [64][1024]
    const ushort_t* __restrict__ hs_lo,
    ushort_t* __restrict__ hd_hi,
    ushort_t* __restrict__ hd_lo,
    float* __restrict__ c_ws,               // [64][1024]
    int tl)
{
  __shared__ float gl[64][33];              // [bat][G-off], padded

  int w = blockIdx.x;
  int tid = threadIdx.x, lane = tid & 63, q = tid >> 6;
  int lm = lane & 15, lk = lane >> 4;

  const ushort_t* ha  = hs_hi + (size_t)(16 * q + lm) * 1024 + lk * 8;
  const ushort_t* la  = hs_lo + (size_t)(16 * q + lm) * 1024 + lk * 8;
  const ushort_t* hb0 = whh_hi + (size_t)(32 * w + lm) * 1024 + lk * 8;
  const ushort_t* lb0 = whh_lo + (size_t)(32 * w + lm) * 1024 + lk * 8;
  const ushort_t* hb1 = hb0 + 16 * 1024;
  const ushort_t* lb1 = lb0 + 16 * 1024;

  f32x4 acc0 = {}, acc1 = {};
#pragma unroll
  for (int kk = 0; kk < 32; ++kk) {
    int o = kk * 32;
    s16x8 ah  = *(const s16x8*)(ha + o);
    s16x8 al  = *(const s16x8*)(la + o);
    s16x8 b0h = *(const s16x8*)(hb0 + o);
    s16x8 b0l = *(const s16x8*)(lb0 + o);
    s16x8 b1h = *(const s16x8*)(hb1 + o);
    s16x8 b1l = *(const s16x8*)(lb1 + o);
    acc0 = __builtin_amdgcn_mfma_f32_16x16x32_bf16(ah, b0h, acc0, 0, 0, 0);
    acc0 = __builtin_amdgcn_mfma_f32_16x16x32_bf16(al, b0h, acc0, 0, 0, 0);
    acc0 = __builtin_amdgcn_mfma_f32_16x16x32_bf16(ah, b0l, acc0, 0, 0, 0);
    acc1 = __builtin_amdgcn_mfma_f32_16x16x32_bf16(ah, b1h, acc1, 0, 0, 0);
    acc1 = __builtin_amdgcn_mfma_f32_16x16x32_bf16(al, b1h, acc1, 0, 0, 0);
    acc1 = __builtin_amdgcn_mfma_f32_16x16x32_bf16(ah, b1l, acc1, 0, 0, 0);
  }
#pragma unroll
  for (int r = 0; r < 4; ++r) {
    int bat = 16 * q + lk * 4 + r;
    gl[bat][lm] = acc0[r];
    gl[bat][16 + lm] = acc1[r];
  }
  __syncthreads();

  // elementwise: 512 cells (64 bat x 8 hcol), 2 per thread
  int hc = tid & 7, b0 = tid >> 3;
#pragma unroll
  for (int rep = 0; rep < 2; ++rep) {
    int bat = b0 + rep * 32;
    f32x4 xv = *(const f32x4*)(xp + ((size_t)tl * 64 + bat) * 4096 + 32 * w + hc * 4);
    float gi = gl[bat][hc * 4 + 0] + xv[0];
    float gf = gl[bat][hc * 4 + 1] + xv[1];
    float gg = gl[bat][hc * 4 + 2] + xv[2];
    float go = gl[bat][hc * 4 + 3] + xv[3];
    int hcol = 8 * w + hc;
    size_t ci = (size_t)bat * 1024 + hcol;
    float c = c_ws[ci];
    float iv = sigf(gi), fv = sigf(gf), gv = tanhf_(gg), ov = sigf(go);
    c = fv * c + iv * gv;
    float hv = ov * tanhf_(c);
    c_ws[ci] = c;
    ushort_t h_, l_;
    split2(hv, h_, l_);
    hd_hi[ci] = h_;
    hd_lo[ci] = l_;
  }
}

// ---------------- final linear ----------------
__global__ __launch_bounds__(256) void k_final(
    const ushort_t* __restrict__ h_hi,  // [64][1024]
    const ushort_t* __restrict__ h_lo,
    const float* __restrict__ wlin,     // [512][1024]
    const float* __restrict__ blin,     // [512]
    float* __restrict__ out)            // [32768] = mu | logvar
{
  __shared__ float hrow[1024];
  int bat = blockIdx.x;
  int tid = threadIdx.x;
  for (int j = tid; j < 1024; j += 256)
    hrow[j] = bf2f(h_hi[(size_t)bat * 1024 + j]) + bf2f(h_lo[(size_t)bat * 1024 + j]);
  __syncthreads();
#pragma unroll
  for (int rep = 0; rep < 2; ++rep) {
    int col = tid + rep * 256;
    const float* wl = wlin + (size_t)col * 1024;
    float sum = 0.f;
    for (int k = 0; k < 1024; k += 4) {
      f32x4 wv = *(const f32x4*)(wl + k);
      sum += hrow[k] * wv[0] + hrow[k + 1] * wv[1] + hrow[k + 2] * wv[2] + hrow[k + 3] * wv[3];
    }
    sum += blin[col];
    if (col < 256) out[(size_t)bat * 256 + col] = sum;
    else           out[16384 + (size_t)bat * 256 + (col - 256)] = sum;
  }
}

// ---------------- launcher ----------------
extern "C" void kernel_launch(void* const* d_in, const int* in_sizes, int n_in,
                              void* d_out, int out_size, void* d_ws, size_t ws_size,
                              hipStream_t stream) {
  const float* x     = (const float*)d_in[0];
  const float* w_ih  = (const float*)d_in[1];
  const float* w_hh  = (const float*)d_in[2];
  const float* b     = (const float*)d_in[3];
  const float* w_lin = (const float*)d_in[4];
  const float* b_lin = (const float*)d_in[5];
  float* out = (float*)d_out;

  char* ws = (char*)d_ws;
  float*    xp      = (float*)ws;                           // 134,217,728
  float*    wihR    = (float*)(ws + 134217728LL);           //   8,388,608
  float*    biasR   = (float*)(ws + 142606336LL);           //      16,384
  ushort_t* whhR_hi = (ushort_t*)(ws + 142622720LL);        //   8,388,608
  ushort_t* whhR_lo = (ushort_t*)(ws + 151011328LL);        //   8,388,608
  float*    c_ws    = (float*)(ws + 159399936LL);           //     262,144
  ushort_t* h0hi    = (ushort_t*)(ws + 159662080LL);        //     131,072
  ushort_t* h0lo    = (ushort_t*)(ws + 159793152LL);        //     131,072
  ushort_t* h1hi    = (ushort_t*)(ws + 159924224LL);        //     131,072
  ushort_t* h1lo    = (ushort_t*)(ws + 160055296LL);        //     131,072
  // total: 160,186,368 B

  if (ws_size < 160186368ULL) return;  // failure signature: absmax == max|ref| ~ 0.305

  // zero c and h buffer 0 (contiguous: c_ws, h0hi, h0lo)
  (void)hipMemsetAsync(ws + 159399936LL, 0, 262144 + 131072 + 131072, stream);

  k_prep<<<1024, 256, 0, stream>>>(w_ih, w_hh, b, wihR, biasR, whhR_hi, whhR_lo);

  ushort_t* hh[2] = { h0hi, h1hi };
  ushort_t* hl[2] = { h0lo, h1lo };
  for (int c = 0; c < 8; ++c) {
    k_gemm_chunk<<<2048, 256, 0, stream>>>(x, wihR, biasR, xp, c);
    for (int tl = 0; tl < 128; ++tl) {
      int t = c * 128 + tl;
      int src = t & 1, dst = src ^ 1;
      k_step<<<128, 256, 0, stream>>>(xp, whhR_hi, whhR_lo,
                                      hh[src], hl[src], hh[dst], hl[dst], c_ws, tl);
    }
  }
  // after t=1023 (odd), h_final is in buffer 0
  k_final<<<64, 256, 0, stream>>>(h0hi, h0lo, w_lin, b_lin, out);
}